// Round 1
// baseline (1581.918 us; speedup 1.0000x reference)
//
#include <hip/hip_runtime.h>
#include <cstdint>
#include <cstddef>

#define Gn   3040
#define An   100
#define TOKn 43
#define FSn  75
#define NFn  512
#define XC   384

typedef __attribute__((ext_vector_type(8))) short s16x8;
typedef __attribute__((ext_vector_type(4))) float f32x4;

// split fp32 into hi+lo bf16 (both RNE).  x = hi + lo + O(2^-18 |x|)
__device__ __forceinline__ void split_bf16(float x, unsigned short &h, unsigned short &l)
{
  unsigned u = __float_as_uint(x);
  unsigned r = (u + 0x7fffu + ((u >> 16) & 1u)) & 0xffff0000u;
  h = (unsigned short)(r >> 16);
  float res = x - __uint_as_float(r);
  unsigned v = __float_as_uint(res);
  l = (unsigned short)((v + 0x7fffu + ((v >> 16) & 1u)) >> 16);
}

// ============================================================================
// K1: fused per-graph smile GCN.  One 256-thread block per graph. (unchanged)
// ============================================================================
template<int NB, bool GATHER>
__device__ __forceinline__ void adjT_mm(const float* __restrict__ adjg,
                                        const float* __restrict__ src,
                                        const int* __restrict__ sTok,
                                        int h, int b0, float* acc)
{
  for (int a = 0; a < An; ++a) {
    float e;
    if (GATHER) e = src[sTok[a] * 128 + h];
    else        e = src[a * 128 + h];
    const float* arow = adjg + a * An + b0;
    #pragma unroll
    for (int q = 0; q < NB / 4; ++q) {
      float4 v = *(const float4*)(arow + 4 * q);
      acc[4*q+0] = fmaf(v.x, e, acc[4*q+0]);
      acc[4*q+1] = fmaf(v.y, e, acc[4*q+1]);
      acc[4*q+2] = fmaf(v.z, e, acc[4*q+2]);
      acc[4*q+3] = fmaf(v.w, e, acc[4*q+3]);
    }
  }
}

__global__ __launch_bounds__(256, 2) void smile_kernel(
    const float* __restrict__ mol_adj, const int* __restrict__ enc,
    const float* __restrict__ tok_emb, const float* __restrict__ Wm1,
    const float* __restrict__ Wm2, float* __restrict__ xc)
{
  __shared__ float sX[An * 128];
  __shared__ float sMax[256];
  __shared__ int   sTok[An];

  const int g   = blockIdx.x;
  const int t   = threadIdx.x;
  if (t < An) sTok[t] = enc[g * An + t];
  const int h   = t & 127;
  const int grp = t >> 7;

  {
    const float* W1 = Wm1 + (size_t)g * (FSn * 128);
    float acc[22];
    #pragma unroll
    for (int j = 0; j < 22; ++j) acc[j] = 0.f;
    const int rbase = grp * 22;
    for (int f = 0; f < FSn; ++f) {
      float w = W1[f * 128 + h];
      #pragma unroll
      for (int j = 0; j < 22; ++j) {
        int r = rbase + j; if (r > TOKn - 1) r = TOKn - 1;
        acc[j] = fmaf(tok_emb[r * FSn + f], w, acc[j]);
      }
    }
    #pragma unroll
    for (int j = 0; j < 22; ++j) {
      int r = rbase + j;
      if (r < TOKn) sX[r * 128 + h] = acc[j];
    }
  }
  __syncthreads();

  const float* adjg = mol_adj + (size_t)g * (An * An);
  const int b0 = grp ? 52 : 0;
  const int nb = grp ? 48 : 52;

  float accB[52];
  #pragma unroll
  for (int j = 0; j < 52; ++j) accB[j] = 0.f;
  if (grp == 0) adjT_mm<52, true>(adjg, sX, sTok, h, 0,  accB);
  else          adjT_mm<48, true>(adjg, sX, sTok, h, 52, accB);
  __syncthreads();
  #pragma unroll
  for (int j = 0; j < 52; ++j)
    if (j < nb) sX[(b0 + j) * 128 + h] = accB[j];
  __syncthreads();

  {
    const int l   = t & 63;
    const int w4  = t >> 6;
    const int cb0 = w4 * 25;
    const int k2  = 2 * l;
    float accC[50];
    #pragma unroll
    for (int j = 0; j < 50; ++j) accC[j] = 0.f;
    const float* W2 = Wm2 + (size_t)g * (128 * 128);
    for (int hh = 0; hh < 128; hh += 4) {
      float2 wv0 = *(const float2*)&W2[(hh + 0) * 128 + k2];
      float2 wv1 = *(const float2*)&W2[(hh + 1) * 128 + k2];
      float2 wv2 = *(const float2*)&W2[(hh + 2) * 128 + k2];
      float2 wv3 = *(const float2*)&W2[(hh + 3) * 128 + k2];
      #pragma unroll
      for (int j = 0; j < 25; ++j) {
        float4 xv = *(const float4*)&sX[(cb0 + j) * 128 + hh];
        accC[2*j  ] = fmaf(xv.x, wv0.x, accC[2*j  ]);
        accC[2*j+1] = fmaf(xv.x, wv0.y, accC[2*j+1]);
        accC[2*j  ] = fmaf(xv.y, wv1.x, accC[2*j  ]);
        accC[2*j+1] = fmaf(xv.y, wv1.y, accC[2*j+1]);
        accC[2*j  ] = fmaf(xv.z, wv2.x, accC[2*j  ]);
        accC[2*j+1] = fmaf(xv.z, wv2.y, accC[2*j+1]);
        accC[2*j  ] = fmaf(xv.w, wv3.x, accC[2*j  ]);
        accC[2*j+1] = fmaf(xv.w, wv3.y, accC[2*j+1]);
      }
    }
    __syncthreads();
    #pragma unroll
    for (int j = 0; j < 25; ++j)
      *(float2*)&sX[(cb0 + j) * 128 + k2] = make_float2(accC[2*j], accC[2*j+1]);
  }
  __syncthreads();

  float accD[52];
  #pragma unroll
  for (int j = 0; j < 52; ++j) accD[j] = 0.f;
  if (grp == 0) adjT_mm<52, false>(adjg, sX, sTok, h, 0,  accD);
  else          adjT_mm<48, false>(adjg, sX, sTok, h, 52, accD);
  {
    float m = -3.4e38f;
    #pragma unroll
    for (int j = 0; j < 52; ++j)
      if (j < nb) m = fmaxf(m, accD[j]);
    sMax[t] = m;
  }
  __syncthreads();
  if (t < 128) {
    float v = fmaxf(sMax[t], sMax[128 + t]);
    xc[(size_t)g * NFn + XC + t] = v;
  }
}

// ============================================================================
// gemm64: C[M,N] = A[M,K] @ B[K,N], optional relu.  (unchanged, fp32)
// ============================================================================
__global__ __launch_bounds__(256, 2) void gemm64_kernel(
    const float* __restrict__ A0, const float* __restrict__ A1,
    const float* __restrict__ B0, const float* __restrict__ B1,
    float* __restrict__ C0, float* __restrict__ C1,
    int M, int N, int K, int relu)
{
  const float* A = blockIdx.z ? A1 : A0;
  const float* B = blockIdx.z ? B1 : B0;
  float*       C = blockIdx.z ? C1 : C0;

  __shared__ float As[16][68];
  __shared__ float Bs[16][68];

  const int t  = threadIdx.x;
  const int m0 = blockIdx.x * 64, n0 = blockIdx.y * 64;
  const int tx = t & 15, ty = t >> 4;
  const int am = t >> 2,  ak = (t & 3) * 4;
  const int bk = t >> 4,  bn = (t & 15) * 4;

  float acc[4][4];
  #pragma unroll
  for (int i = 0; i < 4; ++i)
    #pragma unroll
    for (int j = 0; j < 4; ++j) acc[i][j] = 0.f;

  for (int k0 = 0; k0 < K; k0 += 16) {
    float4 av = make_float4(0.f, 0.f, 0.f, 0.f);
    if (m0 + am < M) av = *(const float4*)&A[(size_t)(m0 + am) * K + k0 + ak];
    float4 bv = *(const float4*)&B[(size_t)(k0 + bk) * N + n0 + bn];
    __syncthreads();
    As[ak + 0][am] = av.x; As[ak + 1][am] = av.y;
    As[ak + 2][am] = av.z; As[ak + 3][am] = av.w;
    *(float4*)&Bs[bk][bn] = bv;
    __syncthreads();
    #pragma unroll
    for (int kk = 0; kk < 16; ++kk) {
      float4 a4 = *(const float4*)&As[kk][ty * 4];
      float4 b4 = *(const float4*)&Bs[kk][tx * 4];
      const float aa[4] = {a4.x, a4.y, a4.z, a4.w};
      const float bb[4] = {b4.x, b4.y, b4.z, b4.w};
      #pragma unroll
      for (int i = 0; i < 4; ++i)
        #pragma unroll
        for (int j = 0; j < 4; ++j)
          acc[i][j] = fmaf(aa[i], bb[j], acc[i][j]);
    }
  }
  #pragma unroll
  for (int i = 0; i < 4; ++i) {
    int m = m0 + ty * 4 + i;
    if (m < M) {
      float4 v = make_float4(acc[i][0], acc[i][1], acc[i][2], acc[i][3]);
      if (relu) {
        v.x = fmaxf(v.x, 0.f); v.y = fmaxf(v.y, 0.f);
        v.z = fmaxf(v.z, 0.f); v.w = fmaxf(v.w, 0.f);
      }
      *(float4*)&C[(size_t)m * N + n0 + tx * 4] = v;
    }
  }
}

// ============================================================================
// convT: S [G][256] fp32  ->  H,L [256][G] bf16 hi/lo (transposed split).
// blockIdx.z picks (S0->H0,L0) vs (S1->H1,L1).  Grid (95, 8, 2).
// ============================================================================
__global__ __launch_bounds__(256) void convT_kernel(
    const float* __restrict__ S0, const float* __restrict__ S1,
    unsigned short* __restrict__ H0, unsigned short* __restrict__ L0,
    unsigned short* __restrict__ H1, unsigned short* __restrict__ L1)
{
  __shared__ float sT[32][33];
  const float* S     = blockIdx.z ? S1 : S0;
  unsigned short* H  = blockIdx.z ? H1 : H0;
  unsigned short* Lo = blockIdx.z ? L1 : L0;
  const int t  = threadIdx.x;
  const int r0 = blockIdx.x * 32;          // over G rows of S
  const int c0 = blockIdx.y * 32;          // over 256 cols of S
  {
    const int i = t >> 3, j0 = (t & 7) * 4;
    float4 v = *(const float4*)&S[(size_t)(r0 + i) * 256 + c0 + j0];
    sT[i][j0] = v.x; sT[i][j0+1] = v.y; sT[i][j0+2] = v.z; sT[i][j0+3] = v.w;
  }
  __syncthreads();
  {
    const int jj = t >> 3, ii0 = (t & 7) * 4;
    unsigned short h[4], lo[4];
    #pragma unroll
    for (int q = 0; q < 4; ++q) split_bf16(sT[ii0 + q][jj], h[q], lo[q]);
    ushort4 hv = make_ushort4(h[0], h[1], h[2], h[3]);
    ushort4 lv = make_ushort4(lo[0], lo[1], lo[2], lo[3]);
    *(ushort4*)&H [(size_t)(c0 + jj) * Gn + r0 + ii0] = hv;
    *(ushort4*)&Lo[(size_t)(c0 + jj) * Gn + r0 + ii0] = lv;
  }
}

// ============================================================================
// mgemm: C = A @ B via bf16x3 split-float MFMA (error ~2^-18, fp32-equivalent).
//   A: fp32 [M][K] row-major, converted hi/lo on the fly.
//   B: if BF32: Bf is fp32 [N][K] (i.e. B^T row-major), on-the-fly convert.
//      else:    Bh/Bl are pre-split bf16 [N][K] (B^T layout).
//   Tile 128x128, BK=32, 4 waves (2x2), wave = 4x4 frags of 16x16x32.
//   Fragment-ordered LDS (lane-linear 16B) -> conflict-free ds_read/ds_write.
//   SPLIT: z = s*2+pair, K chunked by 768, C = Cpair + s*M*N (partials).
// ============================================================================
template<bool SPLIT, bool BF32>
__global__ __launch_bounds__(256, 2) void mgemm_kernel(
    const float* __restrict__ A0, const float* __restrict__ A1,
    const unsigned short* __restrict__ Bh0, const unsigned short* __restrict__ Bl0,
    const unsigned short* __restrict__ Bh1, const unsigned short* __restrict__ Bl1,
    const float* __restrict__ Bf,
    float* __restrict__ C0, float* __restrict__ C1,
    int M, int N, int K)
{
  // 32 chunks x 1KB: [0,8): A_hi mi, [8,16): A_lo, [16,24): B_hi ni, [24,32): B_lo
  __shared__ __align__(16) unsigned short lds[16384];   // 32 KB

  const int z = blockIdx.z;
  int pair, k0base, kend;
  if (SPLIT) {
    pair = z & 1;
    int s = z >> 1;
    k0base = s * 768;
    kend = k0base + 768; if (kend > K) kend = K;
  } else { pair = 0; k0base = 0; kend = K; }

  const float* A = pair ? A1 : A0;
  const unsigned short* Bh = pair ? Bh1 : Bh0;
  const unsigned short* Bl = pair ? Bl1 : Bl0;
  float* C;
  if (SPLIT) C = (pair ? C1 : C0) + (size_t)(z >> 1) * M * N;
  else       C = C0;

  const int t  = threadIdx.x;
  const int l  = t & 63;
  const int wv = t >> 6;
  const int wr = wv >> 1, wc = wv & 1;
  const int m0 = blockIdx.x * 128, n0 = blockIdx.y * 128;

  const int sm = (t >> 6) * 16 + (t & 15);     // staging row offset (slot 1; slot 2 = +64)
  const int sk = ((t >> 4) & 3) * 8;           // staging k offset within BK=32

  const f32x4 zero4 = {0.f, 0.f, 0.f, 0.f};
  f32x4 acc[4][4];
  #pragma unroll
  for (int i = 0; i < 4; ++i)
    #pragma unroll
    for (int j = 0; j < 4; ++j) acc[i][j] = zero4;

  for (int k0 = k0base; k0 < kend; k0 += 32) {
    // ---- global loads into regs ----
    float4 a00 = make_float4(0.f,0.f,0.f,0.f), a01 = a00, a10 = a00, a11 = a00;
    {
      const size_t base = (size_t)(m0 + sm) * K + k0 + sk;
      if (m0 + sm < M)      { a00 = *(const float4*)&A[base];
                              a01 = *(const float4*)&A[base + 4]; }
      if (m0 + sm + 64 < M) { a10 = *(const float4*)&A[base + (size_t)64 * K];
                              a11 = *(const float4*)&A[base + (size_t)64 * K + 4]; }
    }
    s16x8 b0h, b0l, b1h, b1l;
    float4 bf00, bf01, bf10, bf11;
    if (BF32) {
      bf00 = make_float4(0.f,0.f,0.f,0.f); bf01 = bf00; bf10 = bf00; bf11 = bf00;
      const size_t base = (size_t)(n0 + sm) * K + k0 + sk;
      if (n0 + sm < N)      { bf00 = *(const float4*)&Bf[base];
                              bf01 = *(const float4*)&Bf[base + 4]; }
      if (n0 + sm + 64 < N) { bf10 = *(const float4*)&Bf[base + (size_t)64 * K];
                              bf11 = *(const float4*)&Bf[base + (size_t)64 * K + 4]; }
    } else {
      const size_t base = (size_t)(n0 + sm) * K + k0 + sk;
      b0h = *(const s16x8*)&Bh[base];
      b0l = *(const s16x8*)&Bl[base];
      b1h = *(const s16x8*)&Bh[base + (size_t)64 * K];
      b1l = *(const s16x8*)&Bl[base + (size_t)64 * K];
    }

    // ---- convert to hi/lo bf16 ----
    s16x8 a0h, a0l, a1h, a1l;
    {
      const float av0[8] = {a00.x,a00.y,a00.z,a00.w,a01.x,a01.y,a01.z,a01.w};
      const float av1[8] = {a10.x,a10.y,a10.z,a10.w,a11.x,a11.y,a11.z,a11.w};
      #pragma unroll
      for (int j = 0; j < 8; ++j) {
        unsigned short hh, ll;
        split_bf16(av0[j], hh, ll); a0h[j] = (short)hh; a0l[j] = (short)ll;
        split_bf16(av1[j], hh, ll); a1h[j] = (short)hh; a1l[j] = (short)ll;
      }
    }
    if (BF32) {
      const float bv0[8] = {bf00.x,bf00.y,bf00.z,bf00.w,bf01.x,bf01.y,bf01.z,bf01.w};
      const float bv1[8] = {bf10.x,bf10.y,bf10.z,bf10.w,bf11.x,bf11.y,bf11.z,bf11.w};
      #pragma unroll
      for (int j = 0; j < 8; ++j) {
        unsigned short hh, ll;
        split_bf16(bv0[j], hh, ll); b0h[j] = (short)hh; b0l[j] = (short)ll;
        split_bf16(bv1[j], hh, ll); b1h[j] = (short)hh; b1l[j] = (short)ll;
      }
    }

    __syncthreads();     // previous iter's LDS reads complete
    {
      const int sl = (t & 63) * 8;
      const int c1 = t >> 6, c2 = c1 + 4;
      *(s16x8*)&lds[c1 * 512 + sl]          = a0h;
      *(s16x8*)&lds[4096 + c1 * 512 + sl]   = a0l;
      *(s16x8*)&lds[c2 * 512 + sl]          = a1h;
      *(s16x8*)&lds[4096 + c2 * 512 + sl]   = a1l;
      *(s16x8*)&lds[8192  + c1 * 512 + sl]  = b0h;
      *(s16x8*)&lds[12288 + c1 * 512 + sl]  = b0l;
      *(s16x8*)&lds[8192  + c2 * 512 + sl]  = b1h;
      *(s16x8*)&lds[12288 + c2 * 512 + sl]  = b1l;
    }
    __syncthreads();

    // ---- MFMA: acc += Ahi*Bhi + Ahi*Blo + Alo*Bhi ----
    s16x8 vbh[4], vbl[4];
    #pragma unroll
    for (int ni = 0; ni < 4; ++ni) {
      const int c = wc * 4 + ni;
      vbh[ni] = *(const s16x8*)&lds[8192  + c * 512 + l * 8];
      vbl[ni] = *(const s16x8*)&lds[12288 + c * 512 + l * 8];
    }
    #pragma unroll
    for (int mi = 0; mi < 4; ++mi) {
      const int c = wr * 4 + mi;
      s16x8 ah = *(const s16x8*)&lds[c * 512 + l * 8];
      s16x8 al = *(const s16x8*)&lds[4096 + c * 512 + l * 8];
      #pragma unroll
      for (int ni = 0; ni < 4; ++ni) {
        acc[mi][ni] = __builtin_amdgcn_mfma_f32_16x16x32_bf16(ah, vbh[ni], acc[mi][ni], 0, 0, 0);
        acc[mi][ni] = __builtin_amdgcn_mfma_f32_16x16x32_bf16(ah, vbl[ni], acc[mi][ni], 0, 0, 0);
        acc[mi][ni] = __builtin_amdgcn_mfma_f32_16x16x32_bf16(al, vbh[ni], acc[mi][ni], 0, 0, 0);
      }
    }
  }

  // ---- epilogue: C/D layout col = l&15, row = (l>>4)*4 + r  [m89] ----
  #pragma unroll
  for (int mi = 0; mi < 4; ++mi) {
    const int rowb = m0 + (wr * 4 + mi) * 16 + (l >> 4) * 4;
    #pragma unroll
    for (int ni = 0; ni < 4; ++ni) {
      const int col = n0 + (wc * 4 + ni) * 16 + (l & 15);
      if (col < N) {
        #pragma unroll
        for (int r = 0; r < 4; ++r) {
          const int row = rowb + r;
          if (row < M) C[(size_t)row * N + col] = acc[mi][ni][r];
        }
      }
    }
  }
}

// ============================================================================
// reduce over split-K partials (+ optional relu), strided dest  (unchanged)
// ============================================================================
__global__ void reduce_kernel(const float* __restrict__ part, float* __restrict__ dst,
                              int S, int M, int N, int ldc, int coff, int relu)
{
  int i = blockIdx.x * blockDim.x + threadIdx.x;
  int total = M * (N / 4);
  if (i >= total) return;
  int r = i / (N / 4), c = (i % (N / 4)) * 4;
  float4 s = make_float4(0.f, 0.f, 0.f, 0.f);
  for (int j = 0; j < S; ++j) {
    float4 v = *(const float4*)&part[(size_t)j * M * N + (size_t)r * N + c];
    s.x += v.x; s.y += v.y; s.z += v.z; s.w += v.w;
  }
  if (relu) {
    s.x = fmaxf(s.x, 0.f); s.y = fmaxf(s.y, 0.f);
    s.z = fmaxf(s.z, 0.f); s.w = fmaxf(s.w, 0.f);
  }
  *(float4*)&dst[(size_t)r * ldc + coff + c] = s;
}

__global__ void copyx_kernel(const float* __restrict__ x, float* __restrict__ xc)
{
  int i = blockIdx.x * blockDim.x + threadIdx.x;
  int total = Gn * (XC / 4);
  if (i >= total) return;
  int r = i / (XC / 4), c = (i % (XC / 4)) * 4;
  *(float4*)&xc[(size_t)r * NFn + c] = *(const float4*)&x[(size_t)r * XC + c];
}

// ============================================================================
extern "C" void kernel_launch(void* const* d_in, const int* in_sizes, int n_in,
                              void* d_out, int out_size, void* d_ws, size_t ws_size,
                              hipStream_t stream)
{
  const float* x       = (const float*)d_in[0];
  const float* adj_pos = (const float*)d_in[1];
  const float* adj_neg = (const float*)d_in[2];
  const float* mol_adj = (const float*)d_in[3];
  const int*   enc     = (const int*)d_in[4];
  const float* tok_emb = (const float*)d_in[5];
  const float* Wm1     = (const float*)d_in[6];
  const float* Wm2     = (const float*)d_in[7];
  const float* Wp1     = (const float*)d_in[8];
  const float* Wp2     = (const float*)d_in[9];
  const float* Wn1     = (const float*)d_in[10];
  const float* Wn2     = (const float*)d_in[11];
  const float* Wd1     = (const float*)d_in[12];
  const float* Wd2     = (const float*)d_in[13];
  const float* Wd3     = (const float*)d_in[14];
  const float* Wdec    = (const float*)d_in[15];
  float* out = (float*)d_out;
  float* ws  = (float*)d_ws;

  const size_t MN  = (size_t)Gn * 256;   // 778,240
  const size_t MN2 = (size_t)Gn * 512;   // 1,556,480
  size_t o = 0;
  float* xc    = ws + o; o += MN2;
  float* P1    = ws + o; o += MN;
  float* N1    = ws + o; o += MN;
  float* hp    = ws + o; o += MN;
  float* hn    = ws + o; o += MN;
  float* P2    = ws + o; o += MN;
  float* N2    = ws + o; o += MN;
  float* zbuf  = ws + o; o += MN2;
  float* d1    = ws + o; o += MN;
  float* d2    = ws + o; o += MN2;
  float* z3    = ws + o; o += MN;
  float* tb    = ws + o; o += MN;
  float* partP = ws + o; o += 4 * MN;
  float* partN = ws + o; o += 4 * MN;    // total ~17.1M floats = 68.5 MB (unchanged)

  // BT bf16 hi/lo buffers alias d2 (d2 is only live from step 9 onward;
  // BT is only live steps 2b..6).  4 arrays x 256*3040 ushort = 2*MN floats.
  unsigned short* BTPh = (unsigned short*)d2;
  unsigned short* BTPl = BTPh + (size_t)256 * Gn;
  unsigned short* BTNh = BTPh + (size_t)2 * 256 * Gn;
  unsigned short* BTNl = BTPh + (size_t)3 * 256 * Gn;

  dim3 b256(256);

  // 0) xc[:, :384] = x
  copyx_kernel<<<dim3((Gn * (XC / 4) + 255) / 256), b256, 0, stream>>>(x, xc);
  // 1) smile GCN -> xc[:, 384:512]
  smile_kernel<<<dim3(Gn), b256, 0, stream>>>(mol_adj, enc, tok_emb, Wm1, Wm2, xc);
  // 2) P1 = xc@Wp1 ; N1 = xc@Wn1
  gemm64_kernel<<<dim3(48, 4, 2), b256, 0, stream>>>(xc, xc, Wp1, Wn1, P1, N1, Gn, 256, 512, 0);
  // 2b) transpose+split P1,N1 -> BT bf16 hi/lo
  convT_kernel<<<dim3(95, 8, 2), b256, 0, stream>>>(P1, N1, BTPh, BTPl, BTNh, BTNl);
  // 3) partials = adj_{pos,neg} @ {P1,N1}  (bf16x3 MFMA, split-K S=4)
  mgemm_kernel<true, false><<<dim3(24, 2, 8), b256, 0, stream>>>(
      adj_pos, adj_neg, BTPh, BTPl, BTNh, BTNl, (const float*)nullptr,
      partP, partN, Gn, 256, Gn);
  // 4) hp = relu(sum partP) ; hn = relu(sum partN)
  reduce_kernel<<<dim3(760), b256, 0, stream>>>(partP, hp, 4, Gn, 256, 256, 0, 1);
  reduce_kernel<<<dim3(760), b256, 0, stream>>>(partN, hn, 4, Gn, 256, 256, 0, 1);
  // 5) P2 = hp@Wp2 ; N2 = hn@Wn2
  gemm64_kernel<<<dim3(48, 4, 2), b256, 0, stream>>>(hp, hn, Wp2, Wn2, P2, N2, Gn, 256, 256, 0);
  // 5b) transpose+split P2,N2 -> BT bf16 hi/lo
  convT_kernel<<<dim3(95, 8, 2), b256, 0, stream>>>(P2, N2, BTPh, BTPl, BTNh, BTNl);
  // 6) partials = adj_{pos,neg} @ {P2,N2}  (bf16x3 MFMA)
  mgemm_kernel<true, false><<<dim3(24, 2, 8), b256, 0, stream>>>(
      adj_pos, adj_neg, BTPh, BTPl, BTNh, BTNl, (const float*)nullptr,
      partP, partN, Gn, 256, Gn);
  // 7) z = [zp | zn]
  reduce_kernel<<<dim3(760), b256, 0, stream>>>(partP, zbuf, 4, Gn, 256, 512, 0, 0);
  reduce_kernel<<<dim3(760), b256, 0, stream>>>(partN, zbuf, 4, Gn, 256, 512, 256, 0);
  // 8) d1 = relu(z@Wd1)
  gemm64_kernel<<<dim3(48, 4, 1), b256, 0, stream>>>(zbuf, zbuf, Wd1, Wd1, d1, d1, Gn, 256, 512, 1);
  // 9) d2 = relu(d1@Wd2)   (BT buffers dead from here)
  gemm64_kernel<<<dim3(48, 8, 1), b256, 0, stream>>>(d1, d1, Wd2, Wd2, d2, d2, Gn, 512, 256, 1);
  // 10) z3 = d2@Wd3
  gemm64_kernel<<<dim3(48, 4, 1), b256, 0, stream>>>(d2, d2, Wd3, Wd3, z3, z3, Gn, 256, 512, 0);
  // 11) tb = z3@Wdec
  gemm64_kernel<<<dim3(48, 4, 1), b256, 0, stream>>>(z3, z3, Wdec, Wdec, tb, tb, Gn, 256, 256, 0);
  // 12) out = tb @ z3^T   (bf16x3 MFMA, both operands converted on the fly)
  mgemm_kernel<false, true><<<dim3(24, 24, 1), b256, 0, stream>>>(
      tb, tb, (const unsigned short*)nullptr, (const unsigned short*)nullptr,
      (const unsigned short*)nullptr, (const unsigned short*)nullptr,
      z3, out, out, Gn, Gn, 256);
}

// Round 2
// 975.257 us; speedup vs baseline: 1.6221x; 1.6221x over previous
//
#include <hip/hip_runtime.h>
#include <cstdint>
#include <cstddef>

#define Gn   3040
#define An   100
#define TOKn 43
#define FSn  75
#define NFn  512
#define XC   384

typedef __attribute__((ext_vector_type(8))) short s16x8;
typedef __attribute__((ext_vector_type(4))) float f32x4;

// split fp32 into hi+lo bf16 (both RNE).  x = hi + lo + O(2^-16 |x|)
__device__ __forceinline__ void split_bf16(float x, unsigned short &h, unsigned short &l)
{
  unsigned u = __float_as_uint(x);
  unsigned r = (u + 0x7fffu + ((u >> 16) & 1u)) & 0xffff0000u;
  h = (unsigned short)(r >> 16);
  float res = x - __uint_as_float(r);
  unsigned v = __float_as_uint(res);
  l = (unsigned short)((v + 0x7fffu + ((v >> 16) & 1u)) >> 16);
}

#define MFMA3(acc, ah, al, bh, bl)                                              \
  acc = __builtin_amdgcn_mfma_f32_16x16x32_bf16(ah, bh, acc, 0, 0, 0);          \
  acc = __builtin_amdgcn_mfma_f32_16x16x32_bf16(ah, bl, acc, 0, 0, 0);          \
  acc = __builtin_amdgcn_mfma_f32_16x16x32_bf16(al, bh, acc, 0, 0, 0);

// 4 real k-values (cols c..c+3) + 4 zeros -> K32 tail fragment
__device__ __forceinline__ s16x8 tail_frag(const unsigned short* p, bool act)
{
  s16x8 f = {0,0,0,0,0,0,0,0};
  if (act) {
    uint2 v = *(const uint2*)p;
    f[0] = (short)(v.x & 0xffffu); f[1] = (short)(v.x >> 16);
    f[2] = (short)(v.y & 0xffffu); f[3] = (short)(v.y >> 16);
  }
  return f;
}

__device__ __forceinline__ void pack_split4(const f32x4 a, uint2 &ph, uint2 &pl)
{
  unsigned short h[4], l[4];
  #pragma unroll
  for (int r = 0; r < 4; ++r) split_bf16(a[r], h[r], l[r]);
  ph.x = (unsigned)h[0] | ((unsigned)h[1] << 16);
  ph.y = (unsigned)h[2] | ((unsigned)h[3] << 16);
  pl.x = (unsigned)l[0] | ((unsigned)l[1] << 16);
  pl.y = (unsigned)l[2] | ((unsigned)l[3] << 16);
}

// ============================================================================
// prep_tok: tok_emb [43][75] f32 -> tokh/tokl [43][96] bf16 hi/lo (f zero-pad)
// ============================================================================
__global__ void prep_tok_kernel(const float* __restrict__ tok_emb,
                                unsigned short* __restrict__ th,
                                unsigned short* __restrict__ tl)
{
  int i = blockIdx.x * 256 + threadIdx.x;
  if (i >= TOKn * 96) return;
  int r = i / 96, f = i % 96;
  float v = (f < FSn) ? tok_emb[r * FSn + f] : 0.f;
  unsigned short h, l;
  split_bf16(v, h, l);
  th[i] = h; tl[i] = l;
}

// ============================================================================
// smile_mfma: fused per-graph GCN on matrix cores (bf16x3).
// One 512-thread block (8 waves) per graph.  Wave w owns one 16-tile.
//  stage1: X1 = TEg @ Wm1      -> writes X1T[h][a]   (bufA)
//  stage2: g1T = X1T @ adj     -> writes g1[b][h]
//  stage3: f2 = g1 @ Wm2       -> writes f2T[k2][b]  (bufA, reuse)
//  stage4: h2T = f2T @ adj     -> max over b, write xc[:,384:512]
// K=100 = 3*K32 + tail-K32 (4 real + 4 zero lanes, q==0 only).
// ============================================================================
__global__ __launch_bounds__(512, 1) void smile_mfma_kernel(
    const float* __restrict__ mol_adj, const int* __restrict__ enc,
    const unsigned short* __restrict__ tokh, const unsigned short* __restrict__ tokl,
    const float* __restrict__ Wm1, const float* __restrict__ Wm2,
    float* __restrict__ xc)
{
  // 74624 shorts = 149,248 B
  __shared__ __align__(16) unsigned short sm[74624];
  __shared__ int sTok[An];
  unsigned short* adjT_h = sm;              // [100][104]
  unsigned short* adjT_l = sm + 10400;
  unsigned short* bufA_h = sm + 20800;      // [128][104]  X1T then f2T
  unsigned short* bufA_l = sm + 34112;
  unsigned short* g1_h   = sm + 47424;      // [100][136]
  unsigned short* g1_l   = sm + 61024;

  const int g = blockIdx.x;
  const int t = threadIdx.x;
  const int w = t >> 6, l = t & 63;
  const int lr = l & 15, lq = l >> 4;
  const f32x4 z4 = {0.f, 0.f, 0.f, 0.f};
  const s16x8 z8 = {0,0,0,0,0,0,0,0};

  if (t < An) sTok[t] = enc[g * An + t];

  // ---- phase 0: adj -> adjT hi/lo (transposed split) ----
  {
    const float* adjg = mol_adj + (size_t)g * (An * An);
    for (int i = t; i < 2500; i += 512) {
      const int a = i / 25, b4 = (i % 25) * 4;
      float4 v = *(const float4*)&adjg[i * 4];
      unsigned short hh, ll;
      split_bf16(v.x, hh, ll); adjT_h[(b4+0)*104 + a] = hh; adjT_l[(b4+0)*104 + a] = ll;
      split_bf16(v.y, hh, ll); adjT_h[(b4+1)*104 + a] = hh; adjT_l[(b4+1)*104 + a] = ll;
      split_bf16(v.z, hh, ll); adjT_h[(b4+2)*104 + a] = hh; adjT_l[(b4+2)*104 + a] = ll;
      split_bf16(v.w, hh, ll); adjT_h[(b4+3)*104 + a] = hh; adjT_l[(b4+3)*104 + a] = ll;
    }
  }
  __syncthreads();

  // ---- stage 1: X1 = TEg @ Wm1 (M=a 7mi, N=h: ni=w, K=96 3kc) ----
  {
    const int h = 16 * w + lr;
    const float* W1 = Wm1 + (size_t)g * (FSn * 128);
    s16x8 bh[3], bl[3];
    #pragma unroll
    for (int kc = 0; kc < 3; ++kc) {
      #pragma unroll
      for (int j = 0; j < 8; ++j) {
        int f = 32 * kc + 8 * lq + j;
        float v = (f < FSn) ? W1[f * 128 + h] : 0.f;
        unsigned short hh, ll;
        split_bf16(v, hh, ll);
        bh[kc][j] = (short)hh; bl[kc][j] = (short)ll;
      }
    }
    f32x4 acc[7];
    #pragma unroll
    for (int mi = 0; mi < 7; ++mi) acc[mi] = z4;
    #pragma unroll
    for (int mi = 0; mi < 7; ++mi) {
      const int a = 16 * mi + lr;
      const bool va = a < An;
      const int tk = va ? sTok[a] : 0;
      const unsigned short* th = tokh + tk * 96 + 8 * lq;
      const unsigned short* tl = tokl + tk * 96 + 8 * lq;
      #pragma unroll
      for (int kc = 0; kc < 3; ++kc) {
        s16x8 ah = z8, al = z8;
        if (va) { ah = *(const s16x8*)&th[32 * kc]; al = *(const s16x8*)&tl[32 * kc]; }
        MFMA3(acc[mi], ah, al, bh[kc], bl[kc]);
      }
    }
    // write X1T[h][a] (a0..a0+3 contiguous, b64)
    #pragma unroll
    for (int mi = 0; mi < 7; ++mi) {
      const int a0 = 16 * mi + 4 * lq;
      if (a0 < An) {
        uint2 ph, pl;
        pack_split4(acc[mi], ph, pl);
        *(uint2*)&bufA_h[h * 104 + a0] = ph;
        *(uint2*)&bufA_l[h * 104 + a0] = pl;
      }
    }
  }
  __syncthreads();

  // ---- stage 2: g1T = X1T @ adj (M=h: mi=w, N=b 7ni, K=100) ----
  {
    const unsigned short* xh = &bufA_h[(16 * w + lr) * 104];
    const unsigned short* xl = &bufA_l[(16 * w + lr) * 104];
    f32x4 acc[7];
    #pragma unroll
    for (int ni = 0; ni < 7; ++ni) acc[ni] = z4;
    #pragma unroll
    for (int kc = 0; kc < 4; ++kc) {
      s16x8 ah, al;
      if (kc < 3) {
        ah = *(const s16x8*)&xh[32 * kc + 8 * lq];
        al = *(const s16x8*)&xl[32 * kc + 8 * lq];
      } else {
        ah = tail_frag(xh + 96, lq == 0);
        al = tail_frag(xl + 96, lq == 0);
      }
      #pragma unroll
      for (int ni = 0; ni < 7; ++ni) {
        const int b = 16 * ni + lr;
        const bool vb = b < An;
        s16x8 bh = z8, bl = z8;
        if (kc < 3) {
          if (vb) {
            bh = *(const s16x8*)&adjT_h[b * 104 + 32 * kc + 8 * lq];
            bl = *(const s16x8*)&adjT_l[b * 104 + 32 * kc + 8 * lq];
          }
        } else {
          bh = tail_frag(&adjT_h[b * 104 + 96], vb && lq == 0);
          bl = tail_frag(&adjT_l[b * 104 + 96], vb && lq == 0);
        }
        MFMA3(acc[ni], ah, al, bh, bl);
      }
    }
    __syncthreads();   // X1T reads done before stage-3 overwrites bufA? (writes g1 now)
    #pragma unroll
    for (int ni = 0; ni < 7; ++ni) {
      const int b = 16 * ni + lr;
      if (b < An) {
        uint2 ph, pl;
        pack_split4(acc[ni], ph, pl);
        *(uint2*)&g1_h[b * 136 + 16 * w + 4 * lq] = ph;
        *(uint2*)&g1_l[b * 136 + 16 * w + 4 * lq] = pl;
      }
    }
  }
  __syncthreads();

  // ---- stage 3: f2 = g1 @ Wm2 (M=b 7mi, N=k2: ni=w, K=128 4kc) ----
  {
    const int k2 = 16 * w + lr;
    const float* W2 = Wm2 + (size_t)g * (128 * 128);
    s16x8 bh[4], bl[4];
    #pragma unroll
    for (int kc = 0; kc < 4; ++kc) {
      #pragma unroll
      for (int j = 0; j < 8; ++j) {
        float v = W2[(32 * kc + 8 * lq + j) * 128 + k2];
        unsigned short hh, ll;
        split_bf16(v, hh, ll);
        bh[kc][j] = (short)hh; bl[kc][j] = (short)ll;
      }
    }
    f32x4 acc[7];
    #pragma unroll
    for (int mi = 0; mi < 7; ++mi) acc[mi] = z4;
    #pragma unroll
    for (int kc = 0; kc < 4; ++kc) {
      #pragma unroll
      for (int mi = 0; mi < 7; ++mi) {
        const int b = 16 * mi + lr;
        const bool vb = b < An;
        s16x8 ah = z8, al = z8;
        if (vb) {
          ah = *(const s16x8*)&g1_h[b * 136 + 32 * kc + 8 * lq];
          al = *(const s16x8*)&g1_l[b * 136 + 32 * kc + 8 * lq];
        }
        MFMA3(acc[mi], ah, al, bh[kc], bl[kc]);
      }
    }
    __syncthreads();   // all stage-2 bufA reads complete before overwrite
    // write f2T[k2][b]
    #pragma unroll
    for (int mi = 0; mi < 7; ++mi) {
      const int b0 = 16 * mi + 4 * lq;
      if (b0 < An) {
        uint2 ph, pl;
        pack_split4(acc[mi], ph, pl);
        *(uint2*)&bufA_h[k2 * 104 + b0] = ph;
        *(uint2*)&bufA_l[k2 * 104 + b0] = pl;
      }
    }
  }
  __syncthreads();

  // ---- stage 4: h2T = f2T @ adj (M=k2: mi=w, N=b 7ni, K=100) + maxpool ----
  {
    const unsigned short* fh = &bufA_h[(16 * w + lr) * 104];
    const unsigned short* fl = &bufA_l[(16 * w + lr) * 104];
    f32x4 acc[7];
    #pragma unroll
    for (int ni = 0; ni < 7; ++ni) acc[ni] = z4;
    #pragma unroll
    for (int kc = 0; kc < 4; ++kc) {
      s16x8 ah, al;
      if (kc < 3) {
        ah = *(const s16x8*)&fh[32 * kc + 8 * lq];
        al = *(const s16x8*)&fl[32 * kc + 8 * lq];
      } else {
        ah = tail_frag(fh + 96, lq == 0);
        al = tail_frag(fl + 96, lq == 0);
      }
      #pragma unroll
      for (int ni = 0; ni < 7; ++ni) {
        const int b = 16 * ni + lr;
        const bool vb = b < An;
        s16x8 bh = z8, bl = z8;
        if (kc < 3) {
          if (vb) {
            bh = *(const s16x8*)&adjT_h[b * 104 + 32 * kc + 8 * lq];
            bl = *(const s16x8*)&adjT_l[b * 104 + 32 * kc + 8 * lq];
          }
        } else {
          bh = tail_frag(&adjT_h[b * 104 + 96], vb && lq == 0);
          bl = tail_frag(&adjT_l[b * 104 + 96], vb && lq == 0);
        }
        MFMA3(acc[ni], ah, al, bh, bl);
      }
    }
    // max over b: in-lane over ni (masked), then across the 16 lr-lanes
    float mr[4] = {-3.4e38f, -3.4e38f, -3.4e38f, -3.4e38f};
    #pragma unroll
    for (int ni = 0; ni < 7; ++ni) {
      if (16 * ni + lr < An) {
        #pragma unroll
        for (int r = 0; r < 4; ++r) mr[r] = fmaxf(mr[r], acc[ni][r]);
      }
    }
    #pragma unroll
    for (int d = 1; d < 16; d <<= 1) {
      #pragma unroll
      for (int r = 0; r < 4; ++r) mr[r] = fmaxf(mr[r], __shfl_xor(mr[r], d, 64));
    }
    if (lr == 0) {
      const int k2b = 16 * w + 4 * lq;
      #pragma unroll
      for (int r = 0; r < 4; ++r)
        xc[(size_t)g * NFn + XC + k2b + r] = mr[r];
    }
  }
}

// ============================================================================
// gemm64: C[M,N] = A[M,K] @ B[K,N], optional relu.  (unchanged, fp32)
// ============================================================================
__global__ __launch_bounds__(256, 2) void gemm64_kernel(
    const float* __restrict__ A0, const float* __restrict__ A1,
    const float* __restrict__ B0, const float* __restrict__ B1,
    float* __restrict__ C0, float* __restrict__ C1,
    int M, int N, int K, int relu)
{
  const float* A = blockIdx.z ? A1 : A0;
  const float* B = blockIdx.z ? B1 : B0;
  float*       C = blockIdx.z ? C1 : C0;

  __shared__ float As[16][68];
  __shared__ float Bs[16][68];

  const int t  = threadIdx.x;
  const int m0 = blockIdx.x * 64, n0 = blockIdx.y * 64;
  const int tx = t & 15, ty = t >> 4;
  const int am = t >> 2,  ak = (t & 3) * 4;
  const int bk = t >> 4,  bn = (t & 15) * 4;

  float acc[4][4];
  #pragma unroll
  for (int i = 0; i < 4; ++i)
    #pragma unroll
    for (int j = 0; j < 4; ++j) acc[i][j] = 0.f;

  for (int k0 = 0; k0 < K; k0 += 16) {
    float4 av = make_float4(0.f, 0.f, 0.f, 0.f);
    if (m0 + am < M) av = *(const float4*)&A[(size_t)(m0 + am) * K + k0 + ak];
    float4 bv = *(const float4*)&B[(size_t)(k0 + bk) * N + n0 + bn];
    __syncthreads();
    As[ak + 0][am] = av.x; As[ak + 1][am] = av.y;
    As[ak + 2][am] = av.z; As[ak + 3][am] = av.w;
    *(float4*)&Bs[bk][bn] = bv;
    __syncthreads();
    #pragma unroll
    for (int kk = 0; kk < 16; ++kk) {
      float4 a4 = *(const float4*)&As[kk][ty * 4];
      float4 b4 = *(const float4*)&Bs[kk][tx * 4];
      const float aa[4] = {a4.x, a4.y, a4.z, a4.w};
      const float bb[4] = {b4.x, b4.y, b4.z, b4.w};
      #pragma unroll
      for (int i = 0; i < 4; ++i)
        #pragma unroll
        for (int j = 0; j < 4; ++j)
          acc[i][j] = fmaf(aa[i], bb[j], acc[i][j]);
    }
  }
  #pragma unroll
  for (int i = 0; i < 4; ++i) {
    int m = m0 + ty * 4 + i;
    if (m < M) {
      float4 v = make_float4(acc[i][0], acc[i][1], acc[i][2], acc[i][3]);
      if (relu) {
        v.x = fmaxf(v.x, 0.f); v.y = fmaxf(v.y, 0.f);
        v.z = fmaxf(v.z, 0.f); v.w = fmaxf(v.w, 0.f);
      }
      *(float4*)&C[(size_t)m * N + n0 + tx * 4] = v;
    }
  }
}

// ============================================================================
// convT: S [G][256] fp32  ->  H,L [256][G] bf16 hi/lo (transposed split).
// ============================================================================
__global__ __launch_bounds__(256) void convT_kernel(
    const float* __restrict__ S0, const float* __restrict__ S1,
    unsigned short* __restrict__ H0, unsigned short* __restrict__ L0,
    unsigned short* __restrict__ H1, unsigned short* __restrict__ L1)
{
  __shared__ float sT[32][33];
  const float* S     = blockIdx.z ? S1 : S0;
  unsigned short* H  = blockIdx.z ? H1 : H0;
  unsigned short* Lo = blockIdx.z ? L1 : L0;
  const int t  = threadIdx.x;
  const int r0 = blockIdx.x * 32;
  const int c0 = blockIdx.y * 32;
  {
    const int i = t >> 3, j0 = (t & 7) * 4;
    float4 v = *(const float4*)&S[(size_t)(r0 + i) * 256 + c0 + j0];
    sT[i][j0] = v.x; sT[i][j0+1] = v.y; sT[i][j0+2] = v.z; sT[i][j0+3] = v.w;
  }
  __syncthreads();
  {
    const int jj = t >> 3, ii0 = (t & 7) * 4;
    unsigned short h[4], lo[4];
    #pragma unroll
    for (int q = 0; q < 4; ++q) split_bf16(sT[ii0 + q][jj], h[q], lo[q]);
    ushort4 hv = make_ushort4(h[0], h[1], h[2], h[3]);
    ushort4 lv = make_ushort4(lo[0], lo[1], lo[2], lo[3]);
    *(ushort4*)&H [(size_t)(c0 + jj) * Gn + r0 + ii0] = hv;
    *(ushort4*)&Lo[(size_t)(c0 + jj) * Gn + r0 + ii0] = lv;
  }
}

// ============================================================================
// mgemm: C = A @ B via bf16x3 split-float MFMA.  (unchanged from round 0)
// ============================================================================
template<bool SPLIT, bool BF32>
__global__ __launch_bounds__(256, 2) void mgemm_kernel(
    const float* __restrict__ A0, const float* __restrict__ A1,
    const unsigned short* __restrict__ Bh0, const unsigned short* __restrict__ Bl0,
    const unsigned short* __restrict__ Bh1, const unsigned short* __restrict__ Bl1,
    const float* __restrict__ Bf,
    float* __restrict__ C0, float* __restrict__ C1,
    int M, int N, int K)
{
  __shared__ __align__(16) unsigned short lds[16384];   // 32 KB

  const int z = blockIdx.z;
  int pair, k0base, kend;
  if (SPLIT) {
    pair = z & 1;
    int s = z >> 1;
    k0base = s * 768;
    kend = k0base + 768; if (kend > K) kend = K;
  } else { pair = 0; k0base = 0; kend = K; }

  const float* A = pair ? A1 : A0;
  const unsigned short* Bh = pair ? Bh1 : Bh0;
  const unsigned short* Bl = pair ? Bl1 : Bl0;
  float* C;
  if (SPLIT) C = (pair ? C1 : C0) + (size_t)(z >> 1) * M * N;
  else       C = C0;

  const int t  = threadIdx.x;
  const int l  = t & 63;
  const int wv = t >> 6;
  const int wr = wv >> 1, wc = wv & 1;
  const int m0 = blockIdx.x * 128, n0 = blockIdx.y * 128;

  const int sm = (t >> 6) * 16 + (t & 15);
  const int sk = ((t >> 4) & 3) * 8;

  const f32x4 zero4 = {0.f, 0.f, 0.f, 0.f};
  f32x4 acc[4][4];
  #pragma unroll
  for (int i = 0; i < 4; ++i)
    #pragma unroll
    for (int j = 0; j < 4; ++j) acc[i][j] = zero4;

  for (int k0 = k0base; k0 < kend; k0 += 32) {
    float4 a00 = make_float4(0.f,0.f,0.f,0.f), a01 = a00, a10 = a00, a11 = a00;
    {
      const size_t base = (size_t)(m0 + sm) * K + k0 + sk;
      if (m0 + sm < M)      { a00 = *(const float4*)&A[base];
                              a01 = *(const float4*)&A[base + 4]; }
      if (m0 + sm + 64 < M) { a10 = *(const float4*)&A[base + (size_t)64 * K];
                              a11 = *(const float4*)&A[base + (size_t)64 * K + 4]; }
    }
    s16x8 b0h, b0l, b1h, b1l;
    float4 bf00, bf01, bf10, bf11;
    if (BF32) {
      bf00 = make_float4(0.f,0.f,0.f,0.f); bf01 = bf00; bf10 = bf00; bf11 = bf00;
      const size_t base = (size_t)(n0 + sm) * K + k0 + sk;
      if (n0 + sm < N)      { bf00 = *(const float4*)&Bf[base];
                              bf01 = *(const float4*)&Bf[base + 4]; }
      if (n0 + sm + 64 < N) { bf10 = *(const float4*)&Bf[base + (size_t)64 * K];
                              bf11 = *(const float4*)&Bf[base + (size_t)64 * K + 4]; }
    } else {
      const size_t base = (size_t)(n0 + sm) * K + k0 + sk;
      b0h = *(const s16x8*)&Bh[base];
      b0l = *(const s16x8*)&Bl[base];
      b1h = *(const s16x8*)&Bh[base + (size_t)64 * K];
      b1l = *(const s16x8*)&Bl[base + (size_t)64 * K];
    }

    s16x8 a0h, a0l, a1h, a1l;
    {
      const float av0[8] = {a00.x,a00.y,a00.z,a00.w,a01.x,a01.y,a01.z,a01.w};
      const float av1[8] = {a10.x,a10.y,a10.z,a10.w,a11.x,a11.y,a11.z,a11.w};
      #pragma unroll
      for (int j = 0; j < 8; ++j) {
        unsigned short hh, ll;
        split_bf16(av0[j], hh, ll); a0h[j] = (short)hh; a0l[j] = (short)ll;
        split_bf16(av1[j], hh, ll); a1h[j] = (short)hh; a1l[j] = (short)ll;
      }
    }
    if (BF32) {
      const float bv0[8] = {bf00.x,bf00.y,bf00.z,bf00.w,bf01.x,bf01.y,bf01.z,bf01.w};
      const float bv1[8] = {bf10.x,bf10.y,bf10.z,bf10.w,bf11.x,bf11.y,bf11.z,bf11.w};
      #pragma unroll
      for (int j = 0; j < 8; ++j) {
        unsigned short hh, ll;
        split_bf16(bv0[j], hh, ll); b0h[j] = (short)hh; b0l[j] = (short)ll;
        split_bf16(bv1[j], hh, ll); b1h[j] = (short)hh; b1l[j] = (short)ll;
      }
    }

    __syncthreads();
    {
      const int sl = (t & 63) * 8;
      const int c1 = t >> 6, c2 = c1 + 4;
      *(s16x8*)&lds[c1 * 512 + sl]          = a0h;
      *(s16x8*)&lds[4096 + c1 * 512 + sl]   = a0l;
      *(s16x8*)&lds[c2 * 512 + sl]          = a1h;
      *(s16x8*)&lds[4096 + c2 * 512 + sl]   = a1l;
      *(s16x8*)&lds[8192  + c1 * 512 + sl]  = b0h;
      *(s16x8*)&lds[12288 + c1 * 512 + sl]  = b0l;
      *(s16x8*)&lds[8192  + c2 * 512 + sl]  = b1h;
      *(s16x8*)&lds[12288 + c2 * 512 + sl]  = b1l;
    }
    __syncthreads();

    s16x8 vbh[4], vbl[4];
    #pragma unroll
    for (int ni = 0; ni < 4; ++ni) {
      const int c = wc * 4 + ni;
      vbh[ni] = *(const s16x8*)&lds[8192  + c * 512 + l * 8];
      vbl[ni] = *(const s16x8*)&lds[12288 + c * 512 + l * 8];
    }
    #pragma unroll
    for (int mi = 0; mi < 4; ++mi) {
      const int c = wr * 4 + mi;
      s16x8 ah = *(const s16x8*)&lds[c * 512 + l * 8];
      s16x8 al = *(const s16x8*)&lds[4096 + c * 512 + l * 8];
      #pragma unroll
      for (int ni = 0; ni < 4; ++ni) {
        acc[mi][ni] = __builtin_amdgcn_mfma_f32_16x16x32_bf16(ah, vbh[ni], acc[mi][ni], 0, 0, 0);
        acc[mi][ni] = __builtin_amdgcn_mfma_f32_16x16x32_bf16(ah, vbl[ni], acc[mi][ni], 0, 0, 0);
        acc[mi][ni] = __builtin_amdgcn_mfma_f32_16x16x32_bf16(al, vbh[ni], acc[mi][ni], 0, 0, 0);
      }
    }
  }

  #pragma unroll
  for (int mi = 0; mi < 4; ++mi) {
    const int rowb = m0 + (wr * 4 + mi) * 16 + (l >> 4) * 4;
    #pragma unroll
    for (int ni = 0; ni < 4; ++ni) {
      const int col = n0 + (wc * 4 + ni) * 16 + (l & 15);
      if (col < N) {
        #pragma unroll
        for (int r = 0; r < 4; ++r) {
          const int row = rowb + r;
          if (row < M) C[(size_t)row * N + col] = acc[mi][ni][r];
        }
      }
    }
  }
}

// ============================================================================
// reduce over split-K partials (+ optional relu), strided dest  (unchanged)
// ============================================================================
__global__ void reduce_kernel(const float* __restrict__ part, float* __restrict__ dst,
                              int S, int M, int N, int ldc, int coff, int relu)
{
  int i = blockIdx.x * blockDim.x + threadIdx.x;
  int total = M * (N / 4);
  if (i >= total) return;
  int r = i / (N / 4), c = (i % (N / 4)) * 4;
  float4 s = make_float4(0.f, 0.f, 0.f, 0.f);
  for (int j = 0; j < S; ++j) {
    float4 v = *(const float4*)&part[(size_t)j * M * N + (size_t)r * N + c];
    s.x += v.x; s.y += v.y; s.z += v.z; s.w += v.w;
  }
  if (relu) {
    s.x = fmaxf(s.x, 0.f); s.y = fmaxf(s.y, 0.f);
    s.z = fmaxf(s.z, 0.f); s.w = fmaxf(s.w, 0.f);
  }
  *(float4*)&dst[(size_t)r * ldc + coff + c] = s;
}

__global__ void copyx_kernel(const float* __restrict__ x, float* __restrict__ xc)
{
  int i = blockIdx.x * blockDim.x + threadIdx.x;
  int total = Gn * (XC / 4);
  if (i >= total) return;
  int r = i / (XC / 4), c = (i % (XC / 4)) * 4;
  *(float4*)&xc[(size_t)r * NFn + c] = *(const float4*)&x[(size_t)r * XC + c];
}

// ============================================================================
extern "C" void kernel_launch(void* const* d_in, const int* in_sizes, int n_in,
                              void* d_out, int out_size, void* d_ws, size_t ws_size,
                              hipStream_t stream)
{
  const float* x       = (const float*)d_in[0];
  const float* adj_pos = (const float*)d_in[1];
  const float* adj_neg = (const float*)d_in[2];
  const float* mol_adj = (const float*)d_in[3];
  const int*   enc     = (const int*)d_in[4];
  const float* tok_emb = (const float*)d_in[5];
  const float* Wm1     = (const float*)d_in[6];
  const float* Wm2     = (const float*)d_in[7];
  const float* Wp1     = (const float*)d_in[8];
  const float* Wp2     = (const float*)d_in[9];
  const float* Wn1     = (const float*)d_in[10];
  const float* Wn2     = (const float*)d_in[11];
  const float* Wd1     = (const float*)d_in[12];
  const float* Wd2     = (const float*)d_in[13];
  const float* Wd3     = (const float*)d_in[14];
  const float* Wdec    = (const float*)d_in[15];
  float* out = (float*)d_out;
  float* ws  = (float*)d_ws;

  const size_t MN  = (size_t)Gn * 256;   // 778,240
  const size_t MN2 = (size_t)Gn * 512;   // 1,556,480
  size_t o = 0;
  float* xc    = ws + o; o += MN2;
  float* P1    = ws + o; o += MN;
  float* N1    = ws + o; o += MN;
  float* hp    = ws + o; o += MN;
  float* hn    = ws + o; o += MN;
  float* P2    = ws + o; o += MN;
  float* N2    = ws + o; o += MN;
  float* zbuf  = ws + o; o += MN2;
  float* d1    = ws + o; o += MN;
  float* d2    = ws + o; o += MN2;
  float* z3    = ws + o; o += MN;
  float* tb    = ws + o; o += MN;
  float* partP = ws + o; o += 4 * MN;
  float* partN = ws + o; o += 4 * MN;
  // tok_emb bf16 hi/lo, [43][96] each (padded) = 8256 shorts = 4128 floats
  unsigned short* tokh = (unsigned short*)(ws + o);
  unsigned short* tokl = tokh + TOKn * 96; o += 4128;

  // BT bf16 hi/lo buffers alias d2 (dead until step 9; BT live steps 2b..6)
  unsigned short* BTPh = (unsigned short*)d2;
  unsigned short* BTPl = BTPh + (size_t)256 * Gn;
  unsigned short* BTNh = BTPh + (size_t)2 * 256 * Gn;
  unsigned short* BTNl = BTPh + (size_t)3 * 256 * Gn;

  dim3 b256(256);

  // 0) tok_emb split + xc[:, :384] = x
  prep_tok_kernel<<<dim3((TOKn * 96 + 255) / 256), b256, 0, stream>>>(tok_emb, tokh, tokl);
  copyx_kernel<<<dim3((Gn * (XC / 4) + 255) / 256), b256, 0, stream>>>(x, xc);
  // 1) smile GCN (MFMA) -> xc[:, 384:512]
  smile_mfma_kernel<<<dim3(Gn), dim3(512), 0, stream>>>(
      mol_adj, enc, tokh, tokl, Wm1, Wm2, xc);
  // 2) P1 = xc@Wp1 ; N1 = xc@Wn1
  gemm64_kernel<<<dim3(48, 4, 2), b256, 0, stream>>>(xc, xc, Wp1, Wn1, P1, N1, Gn, 256, 512, 0);
  // 2b) transpose+split P1,N1 -> BT bf16 hi/lo
  convT_kernel<<<dim3(95, 8, 2), b256, 0, stream>>>(P1, N1, BTPh, BTPl, BTNh, BTNl);
  // 3) partials = adj_{pos,neg} @ {P1,N1}  (bf16x3 MFMA, split-K S=4)
  mgemm_kernel<true, false><<<dim3(24, 2, 8), b256, 0, stream>>>(
      adj_pos, adj_neg, BTPh, BTPl, BTNh, BTNl, (const float*)nullptr,
      partP, partN, Gn, 256, Gn);
  // 4) hp = relu(sum partP) ; hn = relu(sum partN)
  reduce_kernel<<<dim3(760), b256, 0, stream>>>(partP, hp, 4, Gn, 256, 256, 0, 1);
  reduce_kernel<<<dim3(760), b256, 0, stream>>>(partN, hn, 4, Gn, 256, 256, 0, 1);
  // 5) P2 = hp@Wp2 ; N2 = hn@Wn2
  gemm64_kernel<<<dim3(48, 4, 2), b256, 0, stream>>>(hp, hn, Wp2, Wn2, P2, N2, Gn, 256, 256, 0);
  // 5b) transpose+split P2,N2
  convT_kernel<<<dim3(95, 8, 2), b256, 0, stream>>>(P2, N2, BTPh, BTPl, BTNh, BTNl);
  // 6) partials = adj_{pos,neg} @ {P2,N2}
  mgemm_kernel<true, false><<<dim3(24, 2, 8), b256, 0, stream>>>(
      adj_pos, adj_neg, BTPh, BTPl, BTNh, BTNl, (const float*)nullptr,
      partP, partN, Gn, 256, Gn);
  // 7) z = [zp | zn]
  reduce_kernel<<<dim3(760), b256, 0, stream>>>(partP, zbuf, 4, Gn, 256, 512, 0, 0);
  reduce_kernel<<<dim3(760), b256, 0, stream>>>(partN, zbuf, 4, Gn, 256, 512, 256, 0);
  // 8) d1 = relu(z@Wd1)
  gemm64_kernel<<<dim3(48, 4, 1), b256, 0, stream>>>(zbuf, zbuf, Wd1, Wd1, d1, d1, Gn, 256, 512, 1);
  // 9) d2 = relu(d1@Wd2)   (BT buffers dead from here)
  gemm64_kernel<<<dim3(48, 8, 1), b256, 0, stream>>>(d1, d1, Wd2, Wd2, d2, d2, Gn, 512, 256, 1);
  // 10) z3 = d2@Wd3
  gemm64_kernel<<<dim3(48, 4, 1), b256, 0, stream>>>(d2, d2, Wd3, Wd3, z3, z3, Gn, 256, 512, 0);
  // 11) tb = z3@Wdec
  gemm64_kernel<<<dim3(48, 4, 1), b256, 0, stream>>>(z3, z3, Wdec, Wdec, tb, tb, Gn, 256, 256, 0);
  // 12) out = tb @ z3^T   (bf16x3 MFMA, both operands converted on the fly)
  mgemm_kernel<false, true><<<dim3(24, 24, 1), b256, 0, stream>>>(
      tb, tb, (const unsigned short*)nullptr, (const unsigned short*)nullptr,
      (const unsigned short*)nullptr, (const unsigned short*)nullptr,
      z3, out, out, Gn, Gn, 256);
}